// Round 1
// baseline (35.574 us; speedup 1.0000x reference)
//
#include <hip/hip_runtime.h>

// Problem constants (from reference)
#define V_SZ 100000
#define D_SZ 128
#define B_SZ 4096
#define NEG_SZ 5
#define L_SZ 6

__device__ __forceinline__ float log_sigmoid(float x) {
    // stable: log_sigmoid(x) = min(x, 0) - log1p(exp(-|x|))
    float ax = fabsf(x);
    return fminf(x, 0.0f) - log1pf(__expf(-ax));
}

__device__ __forceinline__ float wave_reduce_sum(float v) {
    // full 64-lane butterfly reduce; all lanes end with the sum
    #pragma unroll
    for (int off = 32; off > 0; off >>= 1) v += __shfl_xor(v, off);
    return v;
}

// One wave per batch element b. Lane i owns dims {2i, 2i+1}.
template <bool ATOMIC>
__global__ __launch_bounds__(256) void skipgram_loss_kernel(
    const float* __restrict__ u_emb,
    const float* __restrict__ v_emb,
    const int* __restrict__ pos_u_idx,
    const int* __restrict__ pos_u_len,
    const int* __restrict__ pos_v_idx,
    const int* __restrict__ pos_v_len,
    const int* __restrict__ neg_v_idx,
    const int* __restrict__ neg_v_len,
    float* __restrict__ out)   // per_b[B] if !ATOMIC, else scalar accum
{
    const int wave = threadIdx.x >> 6;
    const int lane = threadIdx.x & 63;
    const int b = blockIdx.x * 4 + wave;
    if (b >= B_SZ) return;

    const int doff = lane * 2;

    // ---- mean-pool embed_u ----
    float2 eu = make_float2(0.f, 0.f);
    const int nu = pos_u_len[b] + 1;   // in [1, L]
    #pragma unroll
    for (int l = 0; l < L_SZ; ++l) {
        if (l < nu) {
            const int idx = pos_u_idx[b * L_SZ + l];
            const float2 r = *reinterpret_cast<const float2*>(
                &u_emb[(size_t)idx * D_SZ + doff]);
            eu.x += r.x; eu.y += r.y;
        }
    }
    const float inv_nu = 1.0f / (float)nu;
    eu.x *= inv_nu; eu.y *= inv_nu;

    // ---- mean-pool embed_v ----
    float2 ev = make_float2(0.f, 0.f);
    const int nv = pos_v_len[b] + 1;
    #pragma unroll
    for (int l = 0; l < L_SZ; ++l) {
        if (l < nv) {
            const int idx = pos_v_idx[b * L_SZ + l];
            const float2 r = *reinterpret_cast<const float2*>(
                &v_emb[(size_t)idx * D_SZ + doff]);
            ev.x += r.x; ev.y += r.y;
        }
    }
    const float inv_nv = 1.0f / (float)nv;
    ev.x *= inv_nv; ev.y *= inv_nv;

    // ---- positive score ----
    float score = wave_reduce_sum(eu.x * ev.x + eu.y * ev.y);
    float loss = log_sigmoid(score);

    // ---- negatives ----
    #pragma unroll
    for (int n = 0; n < NEG_SZ; ++n) {
        const int m = b * NEG_SZ + n;
        const int nn = neg_v_len[m] + 1;
        float2 en = make_float2(0.f, 0.f);
        #pragma unroll
        for (int l = 0; l < L_SZ; ++l) {
            if (l < nn) {
                const int idx = neg_v_idx[m * L_SZ + l];
                const float2 r = *reinterpret_cast<const float2*>(
                    &v_emb[(size_t)idx * D_SZ + doff]);
                en.x += r.x; en.y += r.y;
            }
        }
        const float inv_nn = 1.0f / (float)nn;
        float ns = wave_reduce_sum((en.x * eu.x + en.y * eu.y) * inv_nn);
        loss += log_sigmoid(-ns);
    }

    if (lane == 0) {
        if (ATOMIC) {
            atomicAdd(out, -loss / (float)B_SZ);
        } else {
            out[b] = loss;
        }
    }
}

__global__ __launch_bounds__(256) void skipgram_reduce_kernel(
    const float* __restrict__ per_b, float* __restrict__ out)
{
    __shared__ float s[4];
    float acc = 0.0f;
    for (int i = threadIdx.x; i < B_SZ; i += 256) acc += per_b[i];
    acc = wave_reduce_sum(acc);
    const int wave = threadIdx.x >> 6;
    const int lane = threadIdx.x & 63;
    if (lane == 0) s[wave] = acc;
    __syncthreads();
    if (threadIdx.x == 0) {
        out[0] = -(s[0] + s[1] + s[2] + s[3]) / (float)B_SZ;
    }
}

extern "C" void kernel_launch(void* const* d_in, const int* in_sizes, int n_in,
                              void* d_out, int out_size, void* d_ws, size_t ws_size,
                              hipStream_t stream) {
    const float* u_emb     = (const float*)d_in[0];
    const float* v_emb     = (const float*)d_in[1];
    const int*   pos_u_idx = (const int*)d_in[2];
    const int*   pos_u_len = (const int*)d_in[3];
    const int*   pos_v_idx = (const int*)d_in[4];
    const int*   pos_v_len = (const int*)d_in[5];
    const int*   neg_v_idx = (const int*)d_in[6];
    const int*   neg_v_len = (const int*)d_in[7];
    float* out = (float*)d_out;

    const int grid = B_SZ / 4;   // 4 waves (4 b's) per 256-thread block

    if (ws_size >= (size_t)B_SZ * sizeof(float)) {
        float* per_b = (float*)d_ws;
        skipgram_loss_kernel<false><<<grid, 256, 0, stream>>>(
            u_emb, v_emb, pos_u_idx, pos_u_len, pos_v_idx, pos_v_len,
            neg_v_idx, neg_v_len, per_b);
        skipgram_reduce_kernel<<<1, 256, 0, stream>>>(per_b, out);
    } else {
        // fallback: atomic accumulation directly into d_out
        hipMemsetAsync(d_out, 0, sizeof(float), stream);
        skipgram_loss_kernel<true><<<grid, 256, 0, stream>>>(
            u_emb, v_emb, pos_u_idx, pos_u_len, pos_v_idx, pos_v_len,
            neg_v_idx, neg_v_len, out);
    }
}

// Round 2
// 29.473 us; speedup vs baseline: 1.2070x; 1.2070x over previous
//
#include <hip/hip_runtime.h>

// Problem constants (from reference)
#define V_SZ 100000
#define D_SZ 128
#define B_SZ 4096
#define NEG_SZ 5
#define L_SZ 6

__device__ __forceinline__ float log_sigmoid(float x) {
    // stable: log_sigmoid(x) = min(x, 0) - log1p(exp(-|x|))
    float ax = fabsf(x);
    return fminf(x, 0.0f) - log1pf(__expf(-ax));
}

__device__ __forceinline__ float wave_reduce_sum(float v) {
    // full 64-lane butterfly reduce; all lanes end with the sum
    #pragma unroll
    for (int off = 32; off > 0; off >>= 1) v += __shfl_xor(v, off);
    return v;
}

// One wave per batch element b. Lane i owns dims {2i, 2i+1}.
// All gathers are issued unconditionally up front (indices beyond the ragged
// length are still valid vocab ids), masking happens at accumulation time.
// This turns 7 serial memory-latency phases into ~1 (42 loads in flight).
template <bool ATOMIC>
__global__ __launch_bounds__(256) void skipgram_loss_kernel(
    const float* __restrict__ u_emb,
    const float* __restrict__ v_emb,
    const int* __restrict__ pos_u_idx,
    const int* __restrict__ pos_u_len,
    const int* __restrict__ pos_v_idx,
    const int* __restrict__ pos_v_len,
    const int* __restrict__ neg_v_idx,
    const int* __restrict__ neg_v_len,
    float* __restrict__ out)   // per_b[B] if !ATOMIC, else scalar accum
{
    const int wave = threadIdx.x >> 6;
    const int lane = threadIdx.x & 63;
    const int b = blockIdx.x * 4 + wave;
    const int doff = lane * 2;

    // ---- lengths (wave-uniform) ----
    const int nu = pos_u_len[b] + 1;   // in [1, L]
    const int nv = pos_v_len[b] + 1;
    int nn[NEG_SZ];
    #pragma unroll
    for (int n = 0; n < NEG_SZ; ++n) nn[n] = neg_v_len[b * NEG_SZ + n] + 1;

    // ---- all indices (independent loads, issue early) ----
    int iu[L_SZ], iv[L_SZ], ing[NEG_SZ][L_SZ];
    #pragma unroll
    for (int l = 0; l < L_SZ; ++l) iu[l] = pos_u_idx[b * L_SZ + l];
    #pragma unroll
    for (int l = 0; l < L_SZ; ++l) iv[l] = pos_v_idx[b * L_SZ + l];
    #pragma unroll
    for (int n = 0; n < NEG_SZ; ++n)
        #pragma unroll
        for (int l = 0; l < L_SZ; ++l)
            ing[n][l] = neg_v_idx[(b * NEG_SZ + n) * L_SZ + l];

    // ---- all row gathers, unconditional ----
    float2 ru[L_SZ], rv[L_SZ], rn[NEG_SZ][L_SZ];
    #pragma unroll
    for (int l = 0; l < L_SZ; ++l)
        ru[l] = *reinterpret_cast<const float2*>(&u_emb[(size_t)iu[l] * D_SZ + doff]);
    #pragma unroll
    for (int l = 0; l < L_SZ; ++l)
        rv[l] = *reinterpret_cast<const float2*>(&v_emb[(size_t)iv[l] * D_SZ + doff]);
    #pragma unroll
    for (int n = 0; n < NEG_SZ; ++n)
        #pragma unroll
        for (int l = 0; l < L_SZ; ++l)
            rn[n][l] = *reinterpret_cast<const float2*>(&v_emb[(size_t)ing[n][l] * D_SZ + doff]);

    // ---- masked accumulation (cndmask, no branches) ----
    float2 eu = make_float2(0.f, 0.f);
    #pragma unroll
    for (int l = 0; l < L_SZ; ++l) {
        eu.x += (l < nu) ? ru[l].x : 0.0f;
        eu.y += (l < nu) ? ru[l].y : 0.0f;
    }
    const float inv_nu = 1.0f / (float)nu;
    eu.x *= inv_nu; eu.y *= inv_nu;

    float2 ev = make_float2(0.f, 0.f);
    #pragma unroll
    for (int l = 0; l < L_SZ; ++l) {
        ev.x += (l < nv) ? rv[l].x : 0.0f;
        ev.y += (l < nv) ? rv[l].y : 0.0f;
    }
    const float inv_nv = 1.0f / (float)nv;

    // positive score: (eu . ev) * inv_nv   (eu already scaled)
    float score = wave_reduce_sum(eu.x * ev.x + eu.y * ev.y) * inv_nv;
    float loss = log_sigmoid(score);

    // ---- negatives ----
    #pragma unroll
    for (int n = 0; n < NEG_SZ; ++n) {
        float2 en = make_float2(0.f, 0.f);
        #pragma unroll
        for (int l = 0; l < L_SZ; ++l) {
            en.x += (l < nn[n]) ? rn[n][l].x : 0.0f;
            en.y += (l < nn[n]) ? rn[n][l].y : 0.0f;
        }
        const float inv_nn = 1.0f / (float)nn[n];
        float ns = wave_reduce_sum(en.x * eu.x + en.y * eu.y) * inv_nn;
        loss += log_sigmoid(-ns);
    }

    if (lane == 0) {
        if (ATOMIC) {
            atomicAdd(out, -loss / (float)B_SZ);
        } else {
            out[b] = loss;
        }
    }
}

__global__ __launch_bounds__(256) void skipgram_reduce_kernel(
    const float* __restrict__ per_b, float* __restrict__ out)
{
    __shared__ float s[4];
    float acc = 0.0f;
    for (int i = threadIdx.x; i < B_SZ; i += 256) acc += per_b[i];
    acc = wave_reduce_sum(acc);
    const int wave = threadIdx.x >> 6;
    const int lane = threadIdx.x & 63;
    if (lane == 0) s[wave] = acc;
    __syncthreads();
    if (threadIdx.x == 0) {
        out[0] = -(s[0] + s[1] + s[2] + s[3]) / (float)B_SZ;
    }
}

extern "C" void kernel_launch(void* const* d_in, const int* in_sizes, int n_in,
                              void* d_out, int out_size, void* d_ws, size_t ws_size,
                              hipStream_t stream) {
    const float* u_emb     = (const float*)d_in[0];
    const float* v_emb     = (const float*)d_in[1];
    const int*   pos_u_idx = (const int*)d_in[2];
    const int*   pos_u_len = (const int*)d_in[3];
    const int*   pos_v_idx = (const int*)d_in[4];
    const int*   pos_v_len = (const int*)d_in[5];
    const int*   neg_v_idx = (const int*)d_in[6];
    const int*   neg_v_len = (const int*)d_in[7];
    float* out = (float*)d_out;

    const int grid = B_SZ / 4;   // 4 waves (4 b's) per 256-thread block

    if (ws_size >= (size_t)B_SZ * sizeof(float)) {
        float* per_b = (float*)d_ws;
        skipgram_loss_kernel<false><<<grid, 256, 0, stream>>>(
            u_emb, v_emb, pos_u_idx, pos_u_len, pos_v_idx, pos_v_len,
            neg_v_idx, neg_v_len, per_b);
        skipgram_reduce_kernel<<<1, 256, 0, stream>>>(per_b, out);
    } else {
        // fallback: atomic accumulation directly into d_out
        hipMemsetAsync(d_out, 0, sizeof(float), stream);
        skipgram_loss_kernel<true><<<grid, 256, 0, stream>>>(
            u_emb, v_emb, pos_u_idx, pos_u_len, pos_v_idx, pos_v_len,
            neg_v_idx, neg_v_len, out);
    }
}

// Round 3
// 27.915 us; speedup vs baseline: 1.2744x; 1.0558x over previous
//
#include <hip/hip_runtime.h>

// Problem constants (from reference)
#define V_SZ 100000
#define D_SZ 128
#define B_SZ 4096
#define NEG_SZ 5
#define L_SZ 6

__device__ __forceinline__ float log_sigmoid(float x) {
    // stable: log_sigmoid(x) = min(x, 0) - log1p(exp(-|x|))
    float ax = fabsf(x);
    return fminf(x, 0.0f) - log1pf(__expf(-ax));
}

__device__ __forceinline__ float wave_reduce_sum(float v) {
    #pragma unroll
    for (int off = 32; off > 0; off >>= 1) v += __shfl_xor(v, off);
    return v;
}

// One BLOCK per batch element b (grid = 4096, 4 waves/block).
// Phrases 0..6 of b:  p=0 -> embed_u, p=1 -> embed_v, p>=2 -> neg p-2.
// Wave w pools phrases {w, w+3} (phrase 3 pooled twice, identical result,
// benign duplicate LDS store). Gathers are float4 (16B/lane): lanes 0-31
// fetch item 2j's row, lanes 32-63 item 2j+1's row -> 3 gathers per phrase.
// All gathers unconditional (padding indices are valid vocab ids); ragged
// mask applied at accumulation. Wave 0 then computes all 6 dots from LDS.
template <bool ATOMIC>
__global__ __launch_bounds__(256) void skipgram_loss_kernel(
    const float* __restrict__ u_emb,
    const float* __restrict__ v_emb,
    const int* __restrict__ pos_u_idx,
    const int* __restrict__ pos_u_len,
    const int* __restrict__ pos_v_idx,
    const int* __restrict__ pos_v_len,
    const int* __restrict__ neg_v_idx,
    const int* __restrict__ neg_v_len,
    float* __restrict__ out)   // per_b[B] if !ATOMIC, else scalar accum
{
    __shared__ float lds[7 * D_SZ];

    const int b    = blockIdx.x;
    const int wave = threadIdx.x >> 6;
    const int lane = threadIdx.x & 63;
    const int half = lane >> 5;          // 0: items 0,2,4 ; 1: items 1,3,5
    const int dof  = (lane & 31) * 4;    // 4 dims per lane within a row

    // ---- phrase descriptors (wave-uniform) ----
    const int* idxp[2];
    const float* tab[2];
    int n[2], p[2];
    #pragma unroll
    for (int q = 0; q < 2; ++q) {
        const int pp = wave + 3 * q;     // wave0:{0,3} w1:{1,4} w2:{2,5} w3:{3,6}
        p[q] = pp;
        if (pp == 0) {
            idxp[q] = pos_u_idx + b * L_SZ; tab[q] = u_emb; n[q] = pos_u_len[b] + 1;
        } else if (pp == 1) {
            idxp[q] = pos_v_idx + b * L_SZ; tab[q] = v_emb; n[q] = pos_v_len[b] + 1;
        } else {
            const int m = b * NEG_SZ + pp - 2;
            idxp[q] = neg_v_idx + m * L_SZ; tab[q] = v_emb; n[q] = neg_v_len[m] + 1;
        }
    }

    // ---- all 12 indices (independent, issue early) ----
    int id[2][L_SZ];
    #pragma unroll
    for (int q = 0; q < 2; ++q)
        #pragma unroll
        for (int l = 0; l < L_SZ; ++l) id[q][l] = idxp[q][l];

    // ---- 6 unconditional float4 row-gathers (2 rows per instruction) ----
    float4 r[2][3];
    #pragma unroll
    for (int q = 0; q < 2; ++q)
        #pragma unroll
        for (int j = 0; j < 3; ++j) {
            const int idx = half ? id[q][2 * j + 1] : id[q][2 * j];
            r[q][j] = *reinterpret_cast<const float4*>(
                &tab[q][(size_t)idx * D_SZ + dof]);
        }

    // ---- masked accumulate, combine halves, scale, store to LDS ----
    #pragma unroll
    for (int q = 0; q < 2; ++q) {
        float4 a = make_float4(0.f, 0.f, 0.f, 0.f);
        #pragma unroll
        for (int j = 0; j < 3; ++j) {
            const bool valid = (2 * j + half) < n[q];
            a.x += valid ? r[q][j].x : 0.f;
            a.y += valid ? r[q][j].y : 0.f;
            a.z += valid ? r[q][j].z : 0.f;
            a.w += valid ? r[q][j].w : 0.f;
        }
        a.x += __shfl_xor(a.x, 32);
        a.y += __shfl_xor(a.y, 32);
        a.z += __shfl_xor(a.z, 32);
        a.w += __shfl_xor(a.w, 32);
        const float inv = 1.0f / (float)n[q];
        a.x *= inv; a.y *= inv; a.z *= inv; a.w *= inv;
        if (lane < 32)
            *reinterpret_cast<float4*>(&lds[p[q] * D_SZ + dof]) = a;
    }
    __syncthreads();

    // ---- wave 0: all 6 dots + loss ----
    if (wave == 0) {
        const float2 eu = *reinterpret_cast<const float2*>(&lds[0 * D_SZ + 2 * lane]);
        float s[6];
        #pragma unroll
        for (int k = 0; k < 6; ++k) {
            const float2 vp = *reinterpret_cast<const float2*>(
                &lds[(k + 1) * D_SZ + 2 * lane]);
            s[k] = eu.x * vp.x + eu.y * vp.y;
        }
        #pragma unroll
        for (int k = 0; k < 6; ++k) s[k] = wave_reduce_sum(s[k]);
        if (lane == 0) {
            float loss = log_sigmoid(s[0]);           // positive pair
            #pragma unroll
            for (int k = 1; k < 6; ++k) loss += log_sigmoid(-s[k]);
            if (ATOMIC) atomicAdd(out, -loss / (float)B_SZ);
            else        out[b] = loss;
        }
    }
}

__global__ __launch_bounds__(256) void skipgram_reduce_kernel(
    const float* __restrict__ per_b, float* __restrict__ out)
{
    __shared__ float s[4];
    float acc = 0.0f;
    for (int i = threadIdx.x; i < B_SZ; i += 256) acc += per_b[i];
    acc = wave_reduce_sum(acc);
    const int wave = threadIdx.x >> 6;
    const int lane = threadIdx.x & 63;
    if (lane == 0) s[wave] = acc;
    __syncthreads();
    if (threadIdx.x == 0) {
        out[0] = -(s[0] + s[1] + s[2] + s[3]) / (float)B_SZ;
    }
}

extern "C" void kernel_launch(void* const* d_in, const int* in_sizes, int n_in,
                              void* d_out, int out_size, void* d_ws, size_t ws_size,
                              hipStream_t stream) {
    const float* u_emb     = (const float*)d_in[0];
    const float* v_emb     = (const float*)d_in[1];
    const int*   pos_u_idx = (const int*)d_in[2];
    const int*   pos_u_len = (const int*)d_in[3];
    const int*   pos_v_idx = (const int*)d_in[4];
    const int*   pos_v_len = (const int*)d_in[5];
    const int*   neg_v_idx = (const int*)d_in[6];
    const int*   neg_v_len = (const int*)d_in[7];
    float* out = (float*)d_out;

    if (ws_size >= (size_t)B_SZ * sizeof(float)) {
        float* per_b = (float*)d_ws;
        skipgram_loss_kernel<false><<<B_SZ, 256, 0, stream>>>(
            u_emb, v_emb, pos_u_idx, pos_u_len, pos_v_idx, pos_v_len,
            neg_v_idx, neg_v_len, per_b);
        skipgram_reduce_kernel<<<1, 256, 0, stream>>>(per_b, out);
    } else {
        hipMemsetAsync(d_out, 0, sizeof(float), stream);
        skipgram_loss_kernel<true><<<B_SZ, 256, 0, stream>>>(
            u_emb, v_emb, pos_u_idx, pos_u_len, pos_v_idx, pos_v_len,
            neg_v_idx, neg_v_len, out);
    }
}